// Round 1
// baseline (937.318 us; speedup 1.0000x reference)
//
#include <hip/hip_runtime.h>

#define TT 4096      // B*S tokens
#define SS 2048
#define DD 1024
#define NH 16
#define NE 8
#define DFFC 4096

typedef _Float16 h8  __attribute__((ext_vector_type(8)));
typedef _Float16 h4v __attribute__((ext_vector_type(4)));
typedef _Float16 h2t __attribute__((ext_vector_type(2)));
typedef float    f4  __attribute__((ext_vector_type(4)));

__device__ __forceinline__ f4 mfma16(h8 a, h8 b, f4 c){
  return __builtin_amdgcn_mfma_f32_16x16x32_f16(a, b, c, 0, 0, 0);
}
__device__ __forceinline__ void fsplit(float x, _Float16& hi, _Float16& lo){
  _Float16 h = (_Float16)x; hi = h; lo = (_Float16)(x - (float)h);
}

// ---------------- LayerNorm (fp32 in; MODE0: split-f16 out; MODE1: f32 + f16 out)
template<int MODE>
__global__ __launch_bounds__(256) void ln_kernel(
    const float* __restrict__ in, const float* __restrict__ g, const float* __restrict__ b,
    _Float16* __restrict__ outHi, _Float16* __restrict__ outLo,
    float* __restrict__ outF, _Float16* __restrict__ outH)
{
  const int t = blockIdx.x, tid = threadIdx.x;
  f4 v = ((const f4*)(in + (size_t)t*DD))[tid];
  float s = v.x+v.y+v.z+v.w;
  float q = v.x*v.x+v.y*v.y+v.z*v.z+v.w*v.w;
  #pragma unroll
  for (int off=32; off; off>>=1){ s += __shfl_xor(s,off); q += __shfl_xor(q,off); }
  __shared__ float red[8];
  int wid = tid>>6, lane = tid&63;
  if (lane==0){ red[wid]=s; red[4+wid]=q; }
  __syncthreads();
  s = red[0]+red[1]+red[2]+red[3];
  q = red[4]+red[5]+red[6]+red[7];
  float mean = s * (1.0f/DD);
  float var  = q * (1.0f/DD) - mean*mean;
  float vv = var + 1e-5f;
  float r = rsqrtf(vv);
  r = r * (1.5f - 0.5f*vv*r*r);   // Newton refine -> ~fp32-exact rsqrt
  f4 gv = ((const f4*)g)[tid], bv = ((const f4*)b)[tid];
  #pragma unroll
  for (int j=0;j<4;++j){
    float y = (v[j]-mean)*r*gv[j] + bv[j];
    size_t o = (size_t)t*DD + tid*4 + j;
    if constexpr (MODE==0){ _Float16 hi,lo; fsplit(y,hi,lo); outHi[o]=hi; outLo[o]=lo; }
    else { outF[o]=y; outH[o]=(_Float16)y; }
  }
}

// ---------------- split-precision GEMM: C = A(hi+lo) @ Bf32 + bias (+resid)
// MODE0: C -> split f16 planes.  MODE1: Cf = acc + bias + resid (fp32)
template<int MODE>
__global__ __launch_bounds__(256,2) void gemm_split(
    const _Float16* __restrict__ Ah, const _Float16* __restrict__ Al,
    const float* __restrict__ Bw, const float* __restrict__ bias,
    _Float16* __restrict__ Chi, _Float16* __restrict__ Clo,
    float* __restrict__ Cf, const float* __restrict__ resid,
    int N, int K, int lda, int ldb)
{
  __shared__ __align__(16) _Float16 AsH[128][40], AsL[128][40], BsH[128][40], BsL[128][40];
  const int tid = threadIdx.x, lane = tid & 63, wid = tid >> 6;
  const int l15 = lane & 15, l4 = lane >> 4;
  const int wm = (wid>>1)*64, wn = (wid&1)*64;
  const int tn = blockIdx.x*128, tm = blockIdx.y*128;
  f4 acc[4][4] = {};
  for (int k0 = 0; k0 < K; k0 += 32){
    #pragma unroll
    for (int p=0;p<2;++p){
      int row = p*64 + (tid>>2), seg = tid&3;
      size_t go = (size_t)(tm+row)*lda + k0 + seg*8;
      *(int4*)&AsH[row][seg*8] = *(const int4*)(Ah+go);
      *(int4*)&AsL[row][seg*8] = *(const int4*)(Al+go);
    }
    #pragma unroll
    for (int p=0;p<8;++p){
      int idx = p*256+tid, n = idx&127, k = (idx>>7)*2;
      const float* bp = Bw + (size_t)(k0+k)*ldb + tn + n;
      float b0 = bp[0], b1 = bp[ldb];
      h2t bh, bl; _Float16 hh, ll;
      fsplit(b0,hh,ll); bh[0]=hh; bl[0]=ll;
      fsplit(b1,hh,ll); bh[1]=hh; bl[1]=ll;
      *(h2t*)&BsH[n][k] = bh;
      *(h2t*)&BsL[n][k] = bl;
    }
    __syncthreads();
    h8 a_h[4], a_l[4], b_h[4], b_l[4];
    #pragma unroll
    for (int m=0;m<4;++m){
      a_h[m] = *(const h8*)&AsH[wm+m*16+l15][l4*8];
      a_l[m] = *(const h8*)&AsL[wm+m*16+l15][l4*8];
    }
    #pragma unroll
    for (int n=0;n<4;++n){
      b_h[n] = *(const h8*)&BsH[wn+n*16+l15][l4*8];
      b_l[n] = *(const h8*)&BsL[wn+n*16+l15][l4*8];
    }
    #pragma unroll
    for (int n=0;n<4;++n)
      #pragma unroll
      for (int m=0;m<4;++m){
        acc[m][n] = mfma16(a_h[m], b_h[n], acc[m][n]);
        acc[m][n] = mfma16(a_h[m], b_l[n], acc[m][n]);
        acc[m][n] = mfma16(a_l[m], b_h[n], acc[m][n]);
        acc[m][n] = mfma16(a_l[m], b_l[n], acc[m][n]);
      }
    __syncthreads();
  }
  #pragma unroll
  for (int n=0;n<4;++n){
    int col = tn + wn + n*16 + l15;
    float bv = bias[col];
    #pragma unroll
    for (int m=0;m<4;++m)
      #pragma unroll
      for (int r=0;r<4;++r){
        int rowg = tm + wm + m*16 + l4*4 + r;
        float vv = acc[m][n][r] + bv;
        size_t co = (size_t)rowg*N + col;
        if constexpr (MODE==0){ _Float16 hi,lo; fsplit(vv,hi,lo); Chi[co]=hi; Clo[co]=lo; }
        else { Cf[co] = vv + resid[co]; }
      }
  }
}

// ---------------- flash attention, split-f16 precision
__global__ __launch_bounds__(256,2) void attn_kernel(
    const _Float16* __restrict__ qkvH, const _Float16* __restrict__ qkvL,
    _Float16* __restrict__ oH, _Float16* __restrict__ oL)
{
  __shared__ __align__(16) _Float16 KsH[64][72], KsL[64][72], VtH[64][72], VtL[64][72];
  __shared__ __align__(16) _Float16 PsH[4][32][72], PsL[4][32][72];
  const int tid = threadIdx.x, lane = tid & 63, wid = tid >> 6;
  const int l15 = lane & 15, l4 = lane >> 4;
  const int qt = blockIdx.x, bh = blockIdx.y;
  const int b = bh >> 4, h = bh & 15;
  const size_t t0 = (size_t)b * SS;
  const int qbase = qt*128 + wid*32;

  h8 qh[2][2], ql[2][2];
  #pragma unroll
  for (int m=0;m<2;++m)
    #pragma unroll
    for (int ks=0;ks<2;++ks){
      size_t go = (t0 + qbase + m*16 + l15)*(size_t)3072 + h*64 + ks*32 + l4*8;
      qh[m][ks] = *(const h8*)(qkvH + go);
      ql[m][ks] = *(const h8*)(qkvL + go);
    }

  f4 oacc[2][4] = {};
  float mrun[2][4], lrun[2][4];
  #pragma unroll
  for (int m=0;m<2;++m)
    #pragma unroll
    for (int r=0;r<4;++r){ mrun[m][r] = -1e30f; lrun[m][r]=0.f; }

  for (int kv=0; kv<SS; kv+=64){
    {
      int row = tid >> 2, sg = tid & 3;
      size_t gk = (t0 + kv + row)*(size_t)3072 + 1024 + h*64;
      *(int4*)&KsH[row][sg*8]    = *(const int4*)(qkvH + gk + sg*8);
      *(int4*)&KsH[row][32+sg*8] = *(const int4*)(qkvH + gk + 32 + sg*8);
      *(int4*)&KsL[row][sg*8]    = *(const int4*)(qkvL + gk + sg*8);
      *(int4*)&KsL[row][32+sg*8] = *(const int4*)(qkvL + gk + 32 + sg*8);
      int key = row, d0 = sg*16;
      size_t gv = (t0 + kv + key)*(size_t)3072 + 2048 + h*64 + d0;
      h8 a0 = *(const h8*)(qkvH + gv), a1 = *(const h8*)(qkvH + gv + 8);
      h8 c0 = *(const h8*)(qkvL + gv), c1 = *(const h8*)(qkvL + gv + 8);
      #pragma unroll
      for (int j=0;j<8;++j){
        VtH[d0+j][key]   = a0[j]; VtH[d0+8+j][key] = a1[j];
        VtL[d0+j][key]   = c0[j]; VtL[d0+8+j][key] = c1[j];
      }
    }
    __syncthreads();

    f4 s[2][4] = {};
    #pragma unroll
    for (int n=0;n<4;++n)
      #pragma unroll
      for (int ks=0;ks<2;++ks){
        h8 kh = *(const h8*)&KsH[n*16+l15][ks*32+l4*8];
        h8 kl = *(const h8*)&KsL[n*16+l15][ks*32+l4*8];
        #pragma unroll
        for (int m=0;m<2;++m){
          s[m][n] = mfma16(qh[m][ks], kh, s[m][n]);
          s[m][n] = mfma16(qh[m][ks], kl, s[m][n]);
          s[m][n] = mfma16(ql[m][ks], kh, s[m][n]);
          s[m][n] = mfma16(ql[m][ks], kl, s[m][n]);
        }
      }

    #pragma unroll
    for (int m=0;m<2;++m)
      #pragma unroll
      for (int r=0;r<4;++r){
        float mx = fmaxf(fmaxf(s[m][0][r], s[m][1][r]), fmaxf(s[m][2][r], s[m][3][r]));
        #pragma unroll
        for (int off=1; off<16; off<<=1) mx = fmaxf(mx, __shfl_xor(mx, off));
        float mn = fmaxf(mrun[m][r], mx);
        float alpha = __expf((mrun[m][r]-mn)*0.125f);
        mrun[m][r] = mn;
        float pv0 = __expf((s[m][0][r]-mn)*0.125f);
        float pv1 = __expf((s[m][1][r]-mn)*0.125f);
        float pv2 = __expf((s[m][2][r]-mn)*0.125f);
        float pv3 = __expf((s[m][3][r]-mn)*0.125f);
        float ps = pv0+pv1+pv2+pv3;
        #pragma unroll
        for (int off=1; off<16; off<<=1) ps += __shfl_xor(ps, off);
        lrun[m][r] = lrun[m][r]*alpha + ps;
        #pragma unroll
        for (int nd=0;nd<4;++nd) oacc[m][nd][r] *= alpha;
        int qr = m*16 + l4*4 + r;
        _Float16 ph, pl;
        fsplit(pv0, ph, pl); PsH[wid][qr][l15]    = ph; PsL[wid][qr][l15]    = pl;
        fsplit(pv1, ph, pl); PsH[wid][qr][16+l15] = ph; PsL[wid][qr][16+l15] = pl;
        fsplit(pv2, ph, pl); PsH[wid][qr][32+l15] = ph; PsL[wid][qr][32+l15] = pl;
        fsplit(pv3, ph, pl); PsH[wid][qr][48+l15] = ph; PsL[wid][qr][48+l15] = pl;
      }

    #pragma unroll
    for (int ks=0;ks<2;++ks){
      h8 aph[2], apl[2];
      #pragma unroll
      for (int m=0;m<2;++m){
        aph[m] = *(const h8*)&PsH[wid][m*16+l15][ks*32+l4*8];
        apl[m] = *(const h8*)&PsL[wid][m*16+l15][ks*32+l4*8];
      }
      #pragma unroll
      for (int nd=0;nd<4;++nd){
        h8 vh = *(const h8*)&VtH[nd*16+l15][ks*32+l4*8];
        h8 vl = *(const h8*)&VtL[nd*16+l15][ks*32+l4*8];
        #pragma unroll
        for (int m=0;m<2;++m){
          oacc[m][nd] = mfma16(aph[m], vh, oacc[m][nd]);
          oacc[m][nd] = mfma16(aph[m], vl, oacc[m][nd]);
          oacc[m][nd] = mfma16(apl[m], vh, oacc[m][nd]);
          oacc[m][nd] = mfma16(apl[m], vl, oacc[m][nd]);
        }
      }
    }
    __syncthreads();
  }

  #pragma unroll
  for (int m=0;m<2;++m)
    #pragma unroll
    for (int nd=0;nd<4;++nd)
      #pragma unroll
      for (int r=0;r<4;++r){
        float vv = oacc[m][nd][r] / lrun[m][r];
        size_t go = (t0 + qbase + m*16 + l4*4 + r)*(size_t)DD + h*64 + nd*16 + l15;
        _Float16 hi, lo; fsplit(vv, hi, lo);
        oH[go] = hi; oL[go] = lo;
      }
}

// ---------------- gate: fp32 logits, top-2, softmax weights, expert counts
__global__ __launch_bounds__(64) void gate_kernel(
    const float* __restrict__ h2, const float* __restrict__ gw, const float* __restrict__ gb,
    int* __restrict__ topi, float* __restrict__ topw, int* __restrict__ cnt)
{
  const int t = blockIdx.x, lane = threadIdx.x;
  float acc[8] = {0,0,0,0,0,0,0,0};
  for (int i=0;i<16;++i){
    int d = i*64 + lane;
    float hv = h2[(size_t)t*DD + d];
    const f4* gp = (const f4*)(gw + (size_t)d*8);
    f4 g0 = gp[0], g1 = gp[1];
    acc[0]+=hv*g0.x; acc[1]+=hv*g0.y; acc[2]+=hv*g0.z; acc[3]+=hv*g0.w;
    acc[4]+=hv*g1.x; acc[5]+=hv*g1.y; acc[6]+=hv*g1.z; acc[7]+=hv*g1.w;
  }
  #pragma unroll
  for (int e=0;e<8;++e)
    #pragma unroll
    for (int off=32;off;off>>=1) acc[e]+=__shfl_xor(acc[e],off);
  if (lane==0){
    float lg[8];
    #pragma unroll
    for (int e=0;e<8;++e) lg[e]=acc[e]+gb[e];
    int i0=0; float v0=lg[0];
    #pragma unroll
    for (int e=1;e<8;++e) if (lg[e]>v0){ v0=lg[e]; i0=e; }
    int i1=-1; float v1=-1e30f;
    #pragma unroll
    for (int e=0;e<8;++e) if (e!=i0 && lg[e]>v1){ v1=lg[e]; i1=e; }
    float w0 = 1.f/(1.f+expf(v1-v0));
    topi[2*t]=i0; topi[2*t+1]=i1;
    topw[2*t]=w0; topw[2*t+1]=1.f-w0;
    atomicAdd(&cnt[i0],1); atomicAdd(&cnt[i1],1);
  }
}

__global__ void scan_kernel(const int* __restrict__ cnt, int* __restrict__ offs, int* __restrict__ cursor){
  if (threadIdx.x==0){ int s=0; for(int e=0;e<8;++e){ offs[e]=s; s+=cnt[e]; } offs[8]=s; }
  if (threadIdx.x<8) cursor[threadIdx.x]=0;
}

__global__ __launch_bounds__(256) void scatter_kernel(
    const int* __restrict__ topi, const int* __restrict__ offs, int* __restrict__ cursor,
    int* __restrict__ tokl, int* __restrict__ posof)
{
  int t = blockIdx.x*256 + threadIdx.x;
  #pragma unroll
  for (int k=0;k<2;++k){
    int e = topi[2*t+k];
    int p = atomicAdd(&cursor[e],1);
    int idx = offs[e]+p;
    tokl[idx]=t; posof[2*t+k]=idx;
  }
}

// ---------------- grouped expert GEMM (single f16). MODE0: FF1 gather+bias+relu. MODE1: FF2 bias.
template<int MODE>
__global__ __launch_bounds__(256,2) void gemm_ffn(
    const _Float16* __restrict__ A, const float* __restrict__ Bw, const float* __restrict__ bias,
    _Float16* __restrict__ C, const int* __restrict__ tok, const int* __restrict__ offs,
    int N, int K, int lda)
{
  const int e = blockIdx.z;
  const int off = offs[e], Me = offs[e+1]-off;
  const int tm = blockIdx.y*128;
  if (tm >= Me) return;
  const float* Bp = Bw + (size_t)e*K*N;
  const float* biasp = bias + (size_t)e*N;
  __shared__ __align__(16) _Float16 As[128][40], Bs[128][40];
  const int tid = threadIdx.x, lane = tid&63, wid = tid>>6;
  const int l15 = lane & 15, l4 = lane >> 4;
  const int wm = (wid>>1)*64, wn = (wid&1)*64;
  const int tn = blockIdx.x*128;
  size_t arow[2];
  #pragma unroll
  for (int p=0;p<2;++p){
    int row = p*64 + (tid>>2);
    int lr = min(tm+row, Me-1);
    arow[p] = (MODE==0) ? (size_t)tok[off+lr] : (size_t)(off+lr);
  }
  f4 acc[4][4] = {};
  for (int k0=0;k0<K;k0+=32){
    #pragma unroll
    for (int p=0;p<2;++p){
      int row = p*64 + (tid>>2), seg = tid&3;
      *(int4*)&As[row][seg*8] = *(const int4*)(A + arow[p]*lda + k0 + seg*8);
    }
    #pragma unroll
    for (int p=0;p<8;++p){
      int idx=p*256+tid, n=idx&127, k=(idx>>7)*2;
      const float* bp = Bp + (size_t)(k0+k)*N + tn + n;
      h2t bv; bv[0]=(_Float16)bp[0]; bv[1]=(_Float16)bp[N];
      *(h2t*)&Bs[n][k] = bv;
    }
    __syncthreads();
    h8 av[4], bvv[4];
    #pragma unroll
    for (int m=0;m<4;++m) av[m] = *(const h8*)&As[wm+m*16+l15][l4*8];
    #pragma unroll
    for (int n=0;n<4;++n) bvv[n] = *(const h8*)&Bs[wn+n*16+l15][l4*8];
    #pragma unroll
    for (int n=0;n<4;++n)
      #pragma unroll
      for (int m=0;m<4;++m)
        acc[m][n] = mfma16(av[m], bvv[n], acc[m][n]);
    __syncthreads();
  }
  #pragma unroll
  for (int n=0;n<4;++n){
    int col = tn + wn + n*16 + l15;
    float bb = biasp[col];
    #pragma unroll
    for (int m=0;m<4;++m)
      #pragma unroll
      for (int r=0;r<4;++r){
        int lr = tm + wm + m*16 + l4*4 + r;
        if (lr < Me){
          float vv = acc[m][n][r] + bb;
          if constexpr (MODE==0) vv = fmaxf(vv, 0.f);
          C[(size_t)(off+lr)*N + col] = (_Float16)vv;
        }
      }
  }
}

// ---------------- combine: out = x1 + w0*moe[p0] + w1*moe[p1]
__global__ __launch_bounds__(256) void combine_kernel(
    const float* __restrict__ x1, const _Float16* __restrict__ moe,
    const float* __restrict__ topw, const int* __restrict__ posof, float* __restrict__ out)
{
  int t = blockIdx.x, tid = threadIdx.x;
  size_t o = (size_t)t*DD + tid*4;
  f4 xv = *(const f4*)(x1+o);
  int p0=posof[2*t], p1=posof[2*t+1];
  float w0=topw[2*t], w1=topw[2*t+1];
  h4v m0 = *(const h4v*)(moe + (size_t)p0*DD + tid*4);
  h4v m1 = *(const h4v*)(moe + (size_t)p1*DD + tid*4);
  f4 r;
  #pragma unroll
  for (int j=0;j<4;++j) r[j] = xv[j] + w0*(float)m0[j] + w1*(float)m1[j];
  *(f4*)(out+o) = r;
}

extern "C" void kernel_launch(void* const* d_in, const int* in_sizes, int n_in,
                              void* d_out, int out_size, void* d_ws, size_t ws_size,
                              hipStream_t stream)
{
  (void)in_sizes; (void)n_in; (void)out_size; (void)ws_size;
  const float* x     = (const float*)d_in[0];
  const float* ln1g  = (const float*)d_in[1];
  const float* ln1b  = (const float*)d_in[2];
  const float* wqkv  = (const float*)d_in[3];
  const float* bqkv  = (const float*)d_in[4];
  const float* wo    = (const float*)d_in[5];
  const float* bo    = (const float*)d_in[6];
  const float* ln2g  = (const float*)d_in[7];
  const float* ln2b  = (const float*)d_in[8];
  const float* gatew = (const float*)d_in[9];
  const float* gateb = (const float*)d_in[10];
  const float* W1    = (const float*)d_in[11];
  const float* b1    = (const float*)d_in[12];
  const float* W2    = (const float*)d_in[13];
  const float* b2    = (const float*)d_in[14];
  float* out = (float*)d_out;

  char* w = (char*)d_ws;
  // R1: qkv split (2x25,165,824) aliased later by hid (67,108,864)
  _Float16* qkvH = (_Float16*)(w);
  _Float16* qkvL = (_Float16*)(w + 25165824);
  _Float16* hid  = (_Float16*)(w);
  char* r2 = w + 67108864;
  // R2: h1 split (2x8,388,608) aliased later by h2f (16,777,216) + h2h (8,388,608)
  _Float16* h1H = (_Float16*)(r2);
  _Float16* h1L = (_Float16*)(r2 + 8388608);
  float*    h2f = (float*)(r2);
  _Float16* h2h = (_Float16*)(r2 + 16777216);
  char* r3 = r2 + 25165824;
  // R3: o split (2x8,388,608) aliased later by moe (16,777,216)
  _Float16* oH  = (_Float16*)(r3);
  _Float16* oL  = (_Float16*)(r3 + 8388608);
  _Float16* moe = (_Float16*)(r3);
  char* r4 = r3 + 16777216;
  float* x1 = (float*)(r4);
  char* r5 = r4 + 16777216;
  float* topw  = (float*)(r5);
  int*   topi  = (int*)(r5 + 32768);
  int*   posof = (int*)(r5 + 65536);
  int*   tokl  = (int*)(r5 + 98304);
  int*   cnt   = (int*)(r5 + 131072);
  int*   offs  = (int*)(r5 + 131072 + 64);
  int*   cursor= (int*)(r5 + 131072 + 128);

  ln_kernel<0><<<TT, 256, 0, stream>>>(x, ln1g, ln1b, h1H, h1L, nullptr, nullptr);
  gemm_split<0><<<dim3(3072/128, TT/128), 256, 0, stream>>>(
      h1H, h1L, wqkv, bqkv, qkvH, qkvL, nullptr, nullptr, 3072, 1024, 1024, 3072);
  attn_kernel<<<dim3(SS/128, 2*NH), 256, 0, stream>>>(qkvH, qkvL, oH, oL);
  gemm_split<1><<<dim3(1024/128, TT/128), 256, 0, stream>>>(
      oH, oL, wo, bo, nullptr, nullptr, x1, x, 1024, 1024, 1024, 1024);
  ln_kernel<1><<<TT, 256, 0, stream>>>(x1, ln2g, ln2b, nullptr, nullptr, h2f, h2h);
  hipMemsetAsync(cnt, 0, 8*sizeof(int), stream);
  gate_kernel<<<TT, 64, 0, stream>>>(h2f, gatew, gateb, topi, topw, cnt);
  scan_kernel<<<1, 32, 0, stream>>>(cnt, offs, cursor);
  scatter_kernel<<<TT/256, 256, 0, stream>>>(topi, offs, cursor, tokl, posof);
  gemm_ffn<0><<<dim3(DFFC/128, TT/128, NE), 256, 0, stream>>>(
      h2h, W1, b1, hid, tokl, offs, DFFC, 1024, 1024);
  gemm_ffn<1><<<dim3(DD/128, TT/128, NE), 256, 0, stream>>>(
      hid, W2, b2, moe, tokl, offs, DD, DFFC, DFFC);
  combine_kernel<<<TT, 256, 0, stream>>>(x1, moe, topw, posof, out);
}